// Round 4
// baseline (304.155 us; speedup 1.0000x reference)
//
#include <hip/hip_runtime.h>
#include <math.h>

#define PI_F 3.14159265358979323846f

// Persistent device scratch (rewritten fully on every launch).
__device__ float g_rwT[576 * 64];  // res_proj_w transposed: [p][c]
__device__ float g_dwT[576 * 6];   // data_proj_w transposed: [p][q]
__device__ float g_Ur[64 * 64];    // fixed-circuit unitary, real part [t][s]
__device__ float g_Ui[64 * 64];    // imag part [t][s]
__device__ float g_Zw[64 * 64];    // Zw[t][c] = sum_q out_proj_w[c,q]*sign_q(t)
__device__ float g_sang[48];       // style angles [b][q] (tanh*pi applied)
__device__ float g_cb[64];         // out_proj_b + res_proj_b

// ---------------------------------------------------------------------------
// Prep: 64-thread blocks, launch_bounds(64,1) -> VGPR cap 512, so block 0's
// circuit sim (ar[64]+ai[64] live) stays register-resident (no scratch).
// block 0: circuit unitary; block 1: Zw+cb; block 2: style angles;
// blocks 3..578: weight transposes.
__global__ __launch_bounds__(64, 1) void k_prep(
        const float* __restrict__ style,
        const float* __restrict__ dw, const float* __restrict__ rw,
        const float* __restrict__ s2dw, const float* __restrict__ s2db,
        const float* __restrict__ qcnn, const float* __restrict__ meas,
        const float* __restrict__ outw, const float* __restrict__ outb,
        const float* __restrict__ resb) {
    int bid = blockIdx.x;
    int s = threadIdx.x;

    if (bid >= 3) {
        int i = (bid - 3) * 64 + s;                 // 0..36863
        if (i < 576 * 6) { int q = i / 576, p = i % 576; g_dwT[p * 6 + q] = dw[i]; }
        { int c = i / 576, p = i % 576; g_rwT[p * 64 + c] = rw[i]; }
        return;
    }
    if (bid == 1) {  // Zw row s + combined bias
        float zr[6];
#pragma unroll
        for (int q = 0; q < 6; ++q)
            zr[q] = ((s >> (5 - q)) & 1) ? -1.f : 1.f;
#pragma unroll 8
        for (int c = 0; c < 64; ++c) {
            float z = 0.f;
#pragma unroll
            for (int q = 0; q < 6; ++q) z += outw[c * 6 + q] * zr[q];
            g_Zw[s * 64 + c] = z;
        }
        g_cb[s] = outb[s] + resb[s];
        return;
    }
    if (bid == 2) {  // style angles [b][q]
        if (s < 48) {
            int bb = s / 6, q = s % 6;
            float a = s2db[q];
            for (int j = 0; j < 128; ++j) a += style[bb * 128 + j] * s2dw[q * 128 + j];
            g_sang[s] = tanhf(a) * PI_F;
        }
        return;
    }

    // bid == 0, lane s: simulate fixed circuit on basis state e_s -> column s.
    float ar[64], ai[64];
#pragma unroll
    for (int t = 0; t < 64; ++t) { ar[t] = (t == s) ? 1.f : 0.f; ai[t] = 0.f; }

#pragma unroll
    for (int l = 0; l < 2; ++l) {
#pragma unroll
        for (int wq = 0; wq < 6; ++wq) {
            int mask = 1 << (5 - wq);  // wire wq = bit (5-wq) of state index
            float th = qcnn[((l * 6 + wq) * 2 + 0) * 3];
            float sg, cg; sincosf(0.5f * th, &sg, &cg);
#pragma unroll
            for (int t = 0; t < 64; ++t) {
                if (t & mask) continue;
                int u = t | mask;
                float a0r = ar[t], a0i = ai[t], a1r = ar[u], a1i = ai[u];
                ar[t] = cg * a0r - sg * a1r;  ai[t] = cg * a0i - sg * a1i;
                ar[u] = sg * a0r + cg * a1r;  ai[u] = sg * a0i + cg * a1i;
            }
            float ph = qcnn[((l * 6 + wq) * 2 + 1) * 3];
            float sz, cz; sincosf(0.5f * ph, &sz, &cz);
#pragma unroll
            for (int t = 0; t < 64; ++t) {
                float r = ar[t], im = ai[t];
                if (t & mask) { ar[t] = cz * r - sz * im; ai[t] = cz * im + sz * r; }
                else          { ar[t] = cz * r + sz * im; ai[t] = cz * im - sz * r; }
            }
        }
#pragma unroll
        for (int wq = 0; wq < 6; ++wq) {
            int cm = 1 << (5 - wq);
            int tm = 1 << (5 - ((wq + 1) % 6));
#pragma unroll
            for (int t = 0; t < 64; ++t) {
                if ((t & cm) && !(t & tm)) {
                    int u = t | tm;
                    float r = ar[t], im = ai[t];
                    ar[t] = ar[u]; ai[t] = ai[u];
                    ar[u] = r;     ai[u] = im;
                }
            }
        }
    }
#pragma unroll
    for (int wq = 0; wq < 6; ++wq) {
        int mask = 1 << (5 - wq);
        float th = meas[wq * 3 + 0], ph = meas[wq * 3 + 1], lm = meas[wq * 3 + 2];
        float st2, ct; sincosf(0.5f * th, &st2, &ct);
        float sl, cl;  sincosf(lm, &sl, &cl);
        float sp, cp;  sincosf(ph, &sp, &cp);
        float spl, cpl; sincosf(ph + lm, &spl, &cpl);
        float u01r = -cl * st2, u01i = -sl * st2;
        float u10r =  cp * st2, u10i =  sp * st2;
        float u11r =  cpl * ct, u11i =  spl * ct;
#pragma unroll
        for (int t = 0; t < 64; ++t) {
            if (t & mask) continue;
            int u = t | mask;
            float a0r = ar[t], a0i = ai[t], a1r = ar[u], a1i = ai[u];
            ar[t] = ct * a0r + u01r * a1r - u01i * a1i;
            ai[t] = ct * a0i + u01r * a1i + u01i * a1r;
            ar[u] = u10r * a0r - u10i * a0i + u11r * a1r - u11i * a1i;
            ai[u] = u10r * a0i + u10i * a0r + u11r * a1i + u11i * a1r;
        }
    }
#pragma unroll
    for (int t = 0; t < 64; ++t) { g_Ur[t * 64 + s] = ar[t]; g_Ui[t * 64 + s] = ai[t]; }
}

// ---------------------------------------------------------------------------
// Main: 64 pixels per block (one h-row), 8 slices (waves). Slice owns OUTPUT
// channels / states [8*slice, 8*slice+8). lane == w, so horizontal patch
// neighbors come from lane shuffles instead of extra global loads (3x fewer).
__global__ __launch_bounds__(512, 4) void k_main(const float* __restrict__ x,
                                                 const float* __restrict__ dpb,
                                                 float* __restrict__ out) {
    __shared__ float lds_ang[6 * 512];   // [q][thread]
    __shared__ float lds_psi[64 * 65];   // [pixel][s], stride 65
    __shared__ float lds_prob[64 * 65];  // [pixel][t], stride 65

    int lane  = threadIdx.x & 63;
    int slice = __builtin_amdgcn_readfirstlane(threadIdx.x >> 6);  // 0..7
    int c0 = slice * 8;

    int p = blockIdx.x * 64 + lane;      // pixel id: b*4096 + h*64 + w (w==lane)
    int b = p >> 12;
    int h = (p >> 6) & 63;
    const float* xb = x + (b << 18);

    float acc[8];
#pragma unroll
    for (int k = 0; k < 8; ++k) acc[k] = 0.f;
    float ang[6] = {0.f, 0.f, 0.f, 0.f, 0.f, 0.f};

    // ---- fused conv + angle pass: per (row i, channel c) one coalesced load;
    // w-1 / w+1 via shuffles (edges masked to 0 = image padding).
#pragma unroll
    for (int i = 0; i < 3; ++i) {
        int hh = h + i - 1;
        bool hok = (unsigned)hh < 64u;
        const float* xrow = xb + (hh << 6) + lane;
#pragma unroll 8
        for (int c = 0; c < 64; ++c) {
            float vm = 0.f;
            if (hok) vm = xrow[c << 12];
            float vl = __shfl_up(vm, 1);
            float vr = __shfl_down(vm, 1);
            if (lane == 0)  vl = 0.f;
            if (lane == 63) vr = 0.f;
            const float* wp = g_rwT + ((c * 9 + i * 3) << 6) + c0;  // rows j=0,1,2
            const float4 a0 = *(const float4*)(wp);
            const float4 a1 = *(const float4*)(wp + 4);
            const float4 b0 = *(const float4*)(wp + 64);
            const float4 b1 = *(const float4*)(wp + 68);
            const float4 d0 = *(const float4*)(wp + 128);
            const float4 d1 = *(const float4*)(wp + 132);
            acc[0] += vl * a0.x + vm * b0.x + vr * d0.x;
            acc[1] += vl * a0.y + vm * b0.y + vr * d0.y;
            acc[2] += vl * a0.z + vm * b0.z + vr * d0.z;
            acc[3] += vl * a0.w + vm * b0.w + vr * d0.w;
            acc[4] += vl * a1.x + vm * b1.x + vr * d1.x;
            acc[5] += vl * a1.y + vm * b1.y + vr * d1.y;
            acc[6] += vl * a1.z + vm * b1.z + vr * d1.z;
            acc[7] += vl * a1.w + vm * b1.w + vr * d1.w;
            if ((c >> 3) == slice) {  // this slice's angle channels
                const float* dp = g_dwT + (c * 9 + i * 3) * 6;
#pragma unroll
                for (int q = 0; q < 6; ++q)
                    ang[q] += vl * dp[q] + vm * dp[6 + q] + vr * dp[12 + q];
            }
        }
    }
#pragma unroll
    for (int q = 0; q < 6; ++q) lds_ang[q * 512 + threadIdx.x] = ang[q];

    // ---- reduce angles across the 8 slices, finish theta, sincos
    __syncthreads();
    float sc[6], cc[6];
#pragma unroll
    for (int q = 0; q < 6; ++q) {
        const float* a = lds_ang + q * 512 + lane;
        float t = 0.f;
#pragma unroll
        for (int s2 = 0; s2 < 8; ++s2) t += a[s2 * 64];
        float theta = tanhf(t + dpb[q]) * PI_F + g_sang[b * 6 + q];
        sincosf(0.5f * theta, &sc[q], &cc[q]);
    }

    // ---- cooperative psi: this thread builds states s = c0..c0+7 as
    // 6-factor products (wire q = bit (5-q) of s).
#pragma unroll
    for (int ti = 0; ti < 8; ++ti) {
        int s = c0 + ti;
        float v = ((s >> 5) & 1) ? sc[0] : cc[0];
        v *= ((s >> 4) & 1) ? sc[1] : cc[1];
        v *= ((s >> 3) & 1) ? sc[2] : cc[2];
        v *= ((s >> 2) & 1) ? sc[3] : cc[3];
        v *= ((s >> 1) & 1) ? sc[4] : cc[4];
        v *= (s & 1)        ? sc[5] : cc[5];
        lds_psi[lane * 65 + s] = v;
    }
    __syncthreads();

    // ---- probs for this slice's 8 states: stream psi from LDS in blocks of 8
    float yr[8], yi[8];
#pragma unroll
    for (int t = 0; t < 8; ++t) { yr[t] = 0.f; yi[t] = 0.f; }
#pragma unroll
    for (int s0 = 0; s0 < 8; ++s0) {
        float ps[8];
#pragma unroll
        for (int k = 0; k < 8; ++k) ps[k] = lds_psi[lane * 65 + s0 * 8 + k];
#pragma unroll
        for (int t = 0; t < 8; ++t) {
            const float4 u0 = *(const float4*)(g_Ur + ((c0 + t) << 6) + s0 * 8);
            const float4 u1 = *(const float4*)(g_Ur + ((c0 + t) << 6) + s0 * 8 + 4);
            const float4 v0 = *(const float4*)(g_Ui + ((c0 + t) << 6) + s0 * 8);
            const float4 v1 = *(const float4*)(g_Ui + ((c0 + t) << 6) + s0 * 8 + 4);
            yr[t] += u0.x * ps[0] + u0.y * ps[1] + u0.z * ps[2] + u0.w * ps[3]
                   + u1.x * ps[4] + u1.y * ps[5] + u1.z * ps[6] + u1.w * ps[7];
            yi[t] += v0.x * ps[0] + v0.y * ps[1] + v0.z * ps[2] + v0.w * ps[3]
                   + v1.x * ps[4] + v1.y * ps[5] + v1.z * ps[6] + v1.w * ps[7];
        }
    }
#pragma unroll
    for (int t = 0; t < 8; ++t)
        lds_prob[lane * 65 + c0 + t] = yr[t] * yr[t] + yi[t] * yi[t];
    __syncthreads();

    // ---- fold probs through Zw into this slice's 8 output channels
#pragma unroll 8
    for (int t = 0; t < 64; ++t) {
        float pr = lds_prob[lane * 65 + t];
        const float4 z0 = *(const float4*)(g_Zw + (t << 6) + c0);
        const float4 z1 = *(const float4*)(g_Zw + (t << 6) + c0 + 4);
        acc[0] += pr * z0.x; acc[1] += pr * z0.y;
        acc[2] += pr * z0.z; acc[3] += pr * z0.w;
        acc[4] += pr * z1.x; acc[5] += pr * z1.y;
        acc[6] += pr * z1.z; acc[7] += pr * z1.w;
    }

    // ---- coalesced store: out[b][c][h][w]
    int ob = (b << 18) + (h << 6) + lane;
#pragma unroll
    for (int k = 0; k < 8; ++k) {
        out[ob + ((c0 + k) << 12)] = acc[k] + g_cb[c0 + k];
    }
}

// ---------------------------------------------------------------------------
extern "C" void kernel_launch(void* const* d_in, const int* in_sizes, int n_in,
                              void* d_out, int out_size, void* d_ws, size_t ws_size,
                              hipStream_t stream) {
    const float* x     = (const float*)d_in[0];
    const float* style = (const float*)d_in[1];
    const float* dw    = (const float*)d_in[2];
    const float* dpb   = (const float*)d_in[3];
    const float* s2dw  = (const float*)d_in[4];
    const float* s2db  = (const float*)d_in[5];
    const float* qcnn  = (const float*)d_in[6];
    const float* meas  = (const float*)d_in[7];
    const float* outw  = (const float*)d_in[8];
    const float* outb  = (const float*)d_in[9];
    const float* rw    = (const float*)d_in[10];
    const float* resb  = (const float*)d_in[11];
    float* out = (float*)d_out;

    hipLaunchKernelGGL(k_prep, dim3(579), dim3(64), 0, stream,
                       style, dw, rw, s2dw, s2db, qcnn, meas, outw, outb, resb);
    hipLaunchKernelGGL(k_main, dim3(512), dim3(512), 0, stream, x, dpb, out);
}